// Round 13
// baseline (247.270 us; speedup 1.0000x reference)
//
#include <hip/hip_runtime.h>
#include <cmath>

typedef unsigned short u16;
typedef __attribute__((ext_vector_type(8))) short bf16x8;
typedef __attribute__((ext_vector_type(4))) float f32x4;
typedef __attribute__((ext_vector_type(16))) float f32x16;

#define MFMA(a,b,c)   __builtin_amdgcn_mfma_f32_16x16x32_bf16((a),(b),(c),0,0,0)
#define MFMA32(a,b,c) __builtin_amdgcn_mfma_f32_32x32x16_bf16((a),(b),(c),0,0,0)

__device__ __forceinline__ float bf2f(u16 u){ return __uint_as_float(((unsigned)u)<<16); }
__device__ __forceinline__ u16 f2bf(float f){
  unsigned x = __float_as_uint(f);
  return (u16)((x + 0x7FFFu + ((x>>16)&1u)) >> 16);
}

__device__ __forceinline__ void gll16(const u16* g, u16* l){
  __builtin_amdgcn_global_load_lds((const __attribute__((address_space(1))) unsigned*)g,
                                   (__attribute__((address_space(3))) unsigned*)l, 16, 0, 0);
}

// ---------- prep: transpose + re-layout to slab-contiguous bf16 ----------
// w1 (E,D,H) -> w1t2[e][kd=d>>4][h][d&15]  (slab (e,kd) = 512 rows x 32B = 16KB)
// w2 (E,H,D) -> w2t2[e][kh=h>>4][d][h&15]  (slab (e,kh) = 256 rows x 32B = 8KB)
__global__ __launch_bounds__(256) void k_transpose(const float* __restrict__ w1,
        const float* __restrict__ w2, u16* __restrict__ w1t2, u16* __restrict__ w2t2){
  __shared__ u16 t[64][66];
  int b = blockIdx.x;
  int c0 = threadIdx.x & 63, r0 = threadIdx.x >> 6;
  if (b < 192){            // w1: src (D=256 x H=512)
    int e = b >> 5, tl = b & 31;
    int tr = (tl >> 3) << 6, tc = (tl & 7) << 6;
    const float* src = w1 + (size_t)e*131072;
    u16* dst = w1t2 + (size_t)e*131072;
    #pragma unroll
    for (int i=0;i<16;++i){
      int r = r0 + i*4;
      t[c0][r] = f2bf(src[(size_t)(tr+r)*512 + tc + c0]);   // coalesced along H
    }
    __syncthreads();
    #pragma unroll
    for (int i=0;i<16;++i){
      int cc = r0 + i*4;
      int h = tc + cc, d = tr + c0;
      dst[(size_t)((d>>4)*512 + h)*16 + (d&15)] = t[cc][c0];
    }
  } else {                 // w2: src (H=512 x D=256)
    int bb = b - 192;
    int e = bb >> 5, tl = bb & 31;
    int tr = (tl >> 2) << 6, tc = (tl & 3) << 6;
    const float* src = w2 + (size_t)e*131072;
    u16* dst = w2t2 + (size_t)e*131072;
    #pragma unroll
    for (int i=0;i<16;++i){
      int r = r0 + i*4;
      t[c0][r] = f2bf(src[(size_t)(tr+r)*256 + tc + c0]);   // coalesced along D
    }
    __syncthreads();
    #pragma unroll
    for (int i=0;i<16;++i){
      int cc = r0 + i*4;
      int d = tc + cc, h = tr + c0;
      dst[(size_t)((h>>4)*256 + d)*16 + (h&15)] = t[cc][c0];
    }
  }
}

// rw1 (261,256): first 256 rows -> [j][d] hi/lo bf16; rows 256..260 + rb1 folded into regb[b][j].
__global__ void k_prep_rw1(const float* __restrict__ rw1, const float* __restrict__ rb1,
                           const float* __restrict__ regime,
                           u16* __restrict__ rwh, u16* __restrict__ rwl,
                           float* __restrict__ regb){
  int idx = blockIdx.x*256 + threadIdx.x;  // 65536 + 2048 total
  if (idx < 65536){
    int dd = idx & 255, j = idx >> 8;
    float w = rw1[dd*256 + j];
    u16 hi = f2bf(w);
    rwh[idx] = hi;
    rwl[idx] = f2bf(w - bf2f(hi));
  } else {
    int i = idx - 65536; int j = i & 255, b = i >> 8;
    float v = rb1[j];
    #pragma unroll
    for (int r=0;r<5;++r) v += regime[b*5+r]*rw1[(256+r)*256 + j];
    regb[b*256 + j] = v;
  }
}

// ---------- LayerNorm: x -> xn hi/lo bf16 (wave per token) ----------
__global__ __launch_bounds__(256) void k_ln(const float* __restrict__ x,
        const float* __restrict__ g, const float* __restrict__ bta,
        u16* __restrict__ xh, u16* __restrict__ xl){
  int wv = threadIdx.x >> 6, lane = threadIdx.x & 63;
  int t = blockIdx.x*4 + wv;
  float4 v = ((const float4*)(x + (size_t)t*256))[lane];
  float s  = v.x+v.y+v.z+v.w;
  float ss = v.x*v.x+v.y*v.y+v.z*v.z+v.w*v.w;
  #pragma unroll
  for (int m=32;m>=1;m>>=1){ s += __shfl_xor(s,m); ss += __shfl_xor(ss,m); }
  float mu  = s*(1.f/256.f);
  float var = ss*(1.f/256.f) - mu*mu;
  float inv = 1.f / sqrtf(var + 1e-5f);
  float4 gv = ((const float4*)g)[lane];
  float4 bv = ((const float4*)bta)[lane];
  float xv[4] = {v.x,v.y,v.z,v.w};
  float gg[4] = {gv.x,gv.y,gv.z,gv.w};
  float bb[4] = {bv.x,bv.y,bv.z,bv.w};
  u16 hh[4], ll[4];
  #pragma unroll
  for (int q=0;q<4;++q){
    float xn = (xv[q]-mu)*inv*gg[q] + bb[q];
    u16 h = f2bf(xn);
    hh[q] = h;
    ll[q] = f2bf(xn - bf2f(h));
  }
  ((ushort4*)(xh + (size_t)t*256))[lane] = make_ushort4(hh[0],hh[1],hh[2],hh[3]);
  ((ushort4*)(xl + (size_t)t*256))[lane] = make_ushort4(ll[0],ll[1],ll[2],ll[3]);
}

// ---------- router GEMM (hi/lo MFMA, weight frags direct from L2) ----------
__global__ __launch_bounds__(256,2) void k_router(const u16* __restrict__ xh, const u16* __restrict__ xl,
        const u16* __restrict__ rwh, const u16* __restrict__ rwl,
        const float* __restrict__ regb, float* __restrict__ hid){
  __shared__ u16 ash[64*264];
  __shared__ u16 asl[64*264];
  int tid = threadIdx.x;
  int lane = tid & 63, wv = tid >> 6;
  int lr = lane & 15, lg = lane >> 4;
  int tb = blockIdx.x * 64;
  for (int c = tid; c < 2048; c += 256){
    int r = c >> 5, cc = c & 31;
    *(uint4*)(&ash[r*264 + cc*8]) = *(const uint4*)(xh + (size_t)(tb+r)*256 + cc*8);
    *(uint4*)(&asl[r*264 + cc*8]) = *(const uint4*)(xl + (size_t)(tb+r)*256 + cc*8);
  }
  __syncthreads();
  f32x4 acc[4][4];
  #pragma unroll
  for (int mf=0;mf<4;++mf)
    #pragma unroll
    for (int nf=0;nf<4;++nf) acc[mf][nf] = (f32x4){0.f,0.f,0.f,0.f};

  const u16* bhb = rwh + (size_t)wv*64*256;
  const u16* blb = rwl + (size_t)wv*64*256;
  #pragma unroll
  for (int kt=0;kt<8;++kt){
    bf16x8 ah[4], al[4], bh[4], bl[4];
    #pragma unroll
    for (int nf=0;nf<4;++nf){
      bh[nf] = *(const bf16x8*)(bhb + (size_t)(nf*16+lr)*256 + kt*32 + lg*8);
      bl[nf] = *(const bf16x8*)(blb + (size_t)(nf*16+lr)*256 + kt*32 + lg*8);
    }
    #pragma unroll
    for (int mf=0;mf<4;++mf){
      ah[mf] = *(const bf16x8*)(&ash[(mf*16+lr)*264 + kt*32 + lg*8]);
      al[mf] = *(const bf16x8*)(&asl[(mf*16+lr)*264 + kt*32 + lg*8]);
    }
    #pragma unroll
    for (int mf=0;mf<4;++mf)
      #pragma unroll
      for (int nf=0;nf<4;++nf){
        acc[mf][nf] = MFMA(ah[mf], bh[nf], acc[mf][nf]);
        acc[mf][nf] = MFMA(al[mf], bh[nf], acc[mf][nf]);
        acc[mf][nf] = MFMA(ah[mf], bl[nf], acc[mf][nf]);
      }
  }
  int b = tb >> 12;
  #pragma unroll
  for (int mf=0;mf<4;++mf)
    #pragma unroll
    for (int nf=0;nf<4;++nf){
      int j = wv*64 + nf*16 + lr;
      float rbv = regb[b*256 + j];
      #pragma unroll
      for (int r=0;r<4;++r){
        int t = tb + mf*16 + lg*4 + r;
        float v = acc[mf][nf][r] + rbv;
        hid[(size_t)t*256 + j] = v/(1.f+__expf(-v));
      }
    }
}

// ---------- logits + top2 + gates + aux partials ----------
__global__ __launch_bounds__(256) void k_logits(const float* __restrict__ hid,
        const float* __restrict__ rw2, const float* __restrict__ rb2,
        float* __restrict__ selw, float* __restrict__ partials){
  __shared__ float psum[6], pcnt[6];
  int tid = threadIdx.x;
  if (tid < 6){ psum[tid]=0.f; pcnt[tid]=0.f; }
  __syncthreads();
  int lane = tid & 63;
  int lr = lane & 15, lg = lane >> 4;
  int t = blockIdx.x*16 + (tid>>6)*4 + lg;
  float lacc[6] = {0.f,0.f,0.f,0.f,0.f,0.f};
  const float4* hp = (const float4*)(hid + (size_t)t*256);
  #pragma unroll
  for (int p=0;p<4;++p){
    float4 h4 = hp[p*16 + lr];
    float hv[4] = {h4.x,h4.y,h4.z,h4.w};
    int j0 = (p*16+lr)*4;
    #pragma unroll
    for (int q=0;q<4;++q)
      #pragma unroll
      for (int e=0;e<6;++e) lacc[e] += hv[q]*rw2[(j0+q)*6+e];
  }
  #pragma unroll
  for (int m=1;m<16;m<<=1)
    #pragma unroll
    for (int e=0;e<6;++e) lacc[e] += __shfl_xor(lacc[e], m);
  if (lr == 0){
    float lgv[6];
    #pragma unroll
    for (int e=0;e<6;++e) lgv[e] = lacc[e] + rb2[e];
    int i0=0; float v0=lgv[0];
    #pragma unroll
    for (int e=1;e<6;++e) if (lgv[e] > v0){ v0=lgv[e]; i0=e; }
    int i1=-1; float v1=-1e30f;
    #pragma unroll
    for (int e=0;e<6;++e) if (e!=i0 && lgv[e] > v1){ v1=lgv[e]; i1=e; }
    float ex = expf(v1-v0);
    float w0 = 1.f/(1.f+ex), w1 = ex/(1.f+ex);
    #pragma unroll
    for (int e=0;e<6;++e) selw[(size_t)t*6+e] = (e==i0)? w0 : (e==i1)? w1 : 0.f;
    float ps=0.f, p[6];
    #pragma unroll
    for (int e=0;e<6;++e){ p[e]=expf(lgv[e]-v0); ps+=p[e]; }
    float rinv = 1.f/ps;
    #pragma unroll
    for (int e=0;e<6;++e) atomicAdd(&psum[e], p[e]*rinv);
    atomicAdd(&pcnt[i0], 1.f);
  }
  __syncthreads();
  if (tid < 6){
    partials[blockIdx.x*12 + tid] = psum[tid];
    partials[blockIdx.x*12 + 6 + tid] = pcnt[tid];
  }
}

__global__ __launch_bounds__(256) void k_aux(const float* __restrict__ partials, float* __restrict__ outp){
  __shared__ float a[12];
  int tid = threadIdx.x;
  if (tid < 12) a[tid] = 0.f;
  __syncthreads();
  int col = tid & 15, seg = tid >> 4;
  if (col < 12){
    float s = 0.f;
    for (int i=seg; i<2048; i+=16) s += partials[i*12+col];
    atomicAdd(&a[col], s);
  }
  __syncthreads();
  if (tid==0){
    float aux=0.f;
    #pragma unroll
    for (int e=0;e<6;++e) aux += a[e]*a[6+e];
    aux *= 0.01f*6.f/(32768.f*32768.f);
    outp[8388608] = aux;
  }
}

// ---------- fused all-expert MLP v9: reuse-2 blocking (64h/64d x 64tok per wave) ----------
// 256 blocks (1/CU), 8 waves, launch_bounds(512,2). Slot-major LDS (conflict-free):
//   xs [s=0..31][tok=0..127] 16B cells -> u16 idx = s*1024 + tok*8            (64 KB)
//   hs [sh=0..31][tok=0..127] at +32768 (per h-half; stores g*silu)           (64 KB)
// Wave wv: wh=wv>>1 owns 64 h-rows (G1) / 64 d-rows (G2); wt=wv&1 owns 64 tokens.
// Per ks-step: 2 weight frags (regs, dual-stream depth-2 prefetch) x 2 LDS frags
// -> 4 MFMA32 (LDS reads per MFMA halved vs r12). Gate folded into hs; b2 rank-6 post-fix.
__global__ __launch_bounds__(512,2) void k_experts(const u16* __restrict__ xh,
        const u16* __restrict__ w1t2, const u16* __restrict__ w2t2,
        const float* __restrict__ b1g, const float* __restrict__ b2g,
        const float* __restrict__ selw, const float* __restrict__ xg,
        float* __restrict__ outp){
  __shared__ u16 lds[65536];
  __shared__ float wsl[768];
  int tid = threadIdx.x;
  int lane = tid & 63, wv = tid >> 6;
  int l31 = lane & 31, l5 = lane >> 5;
  int wh = wv >> 1, wt = wv & 1;
  int tb = blockIdx.x * 128;

  // stage xs: linear LDS dest (slot-major), row-gathered global source
  #pragma unroll
  for (int it=0; it<8; ++it){
    int gcell = it*512 + tid;
    int s = gcell >> 7, tok = gcell & 127;
    gll16(xh + (size_t)(tb+tok)*256 + s*8, lds + gcell*8);
  }
  for (int i=tid;i<768;i+=512) wsl[i] = selw[(size_t)tb*6 + i];
  __syncthreads();

  f32x16 a2[2][2];   // persistent gated output acc: [d-sub a][tok-sub tt]
  #pragma unroll
  for (int a=0;a<2;++a)
    #pragma unroll
    for (int tt=0;tt<2;++tt) a2[a][tt] = (f32x16)(0.f);

  for (int e=0;e<6;++e){
    #pragma unroll
    for (int hh=0;hh<2;++hh){
      // ---- GEMM1: wave owns 64 h-rows (hh*256 + wh*64), 64 toks; K=256 ----
      f32x16 a1[2][2];
      #pragma unroll
      for (int a=0;a<2;++a)
        #pragma unroll
        for (int tt=0;tt<2;++tt) a1[a][tt] = (f32x16)(0.f);
      const u16* w1b = w1t2 + (size_t)e*131072 + (size_t)(hh*256 + wh*64 + l31)*16 + l5*8;
      {
        bf16x8 p00 = *(const bf16x8*)(w1b);
        bf16x8 p10 = *(const bf16x8*)(w1b + 512);
        bf16x8 p01 = *(const bf16x8*)(w1b + 8192);
        bf16x8 p11 = *(const bf16x8*)(w1b + 8192 + 512);
        #pragma unroll
        for (int ks=0; ks<16; ++ks){
          bf16x8 c0 = p00, c1 = p10;
          p00 = p01; p10 = p11;
          if (ks+2 < 16){
            p01 = *(const bf16x8*)(w1b + (ks+2)*8192);
            p11 = *(const bf16x8*)(w1b + (ks+2)*8192 + 512);
          }
          bf16x8 b0 = *(const bf16x8*)&lds[(ks*2+l5)*1024 + (wt*64+l31)*8];
          bf16x8 b1 = *(const bf16x8*)&lds[(ks*2+l5)*1024 + (wt*64+32+l31)*8];
          a1[0][0] = MFMA32(c0, b0, a1[0][0]);
          a1[0][1] = MFMA32(c0, b1, a1[0][1]);
          a1[1][0] = MFMA32(c1, b0, a1[1][0]);
          a1[1][1] = MFMA32(c1, b1, a1[1][1]);
        }
      }
      __syncthreads();   // previous GEMM2's hs readers done
      // ---- epilogue: bias + silu, scaled by gate -> hs (slot-major) ----
      #pragma unroll
      for (int a=0;a<2;++a){
        #pragma unroll
        for (int rq=0;rq<4;++rq){
          float4 b4 = *(const float4*)(b1g + (size_t)e*512 + hh*256 + wh*64 + a*32 + rq*8 + l5*4);
          float bb[4] = {b4.x,b4.y,b4.z,b4.w};
          #pragma unroll
          for (int tt=0;tt<2;++tt){
            float g = wsl[(wt*64+tt*32+l31)*6 + e];
            float sv[4];
            #pragma unroll
            for (int q=0;q<4;++q){
              float v = a1[a][tt][rq*4+q] + bb[q];
              sv[q] = g * (v/(1.f+__expf(-v)));
            }
            unsigned pA = (unsigned)f2bf(sv[0]) | ((unsigned)f2bf(sv[1])<<16);
            unsigned pB = (unsigned)f2bf(sv[2]) | ((unsigned)f2bf(sv[3])<<16);
            *(uint2*)&lds[32768 + (wh*8+a*4+rq)*1024 + (wt*64+tt*32+l31)*8 + l5*4] = make_uint2(pA,pB);
          }
        }
      }
      __syncthreads();   // hs ready
      // ---- GEMM2: wave owns 64 d-rows (wh*64), 64 toks; K = this h-half (256) ----
      const u16* w2b = w2t2 + (size_t)e*131072 + (size_t)(hh*16)*4096 + (size_t)(wh*64 + l31)*16 + l5*8;
      {
        bf16x8 p00 = *(const bf16x8*)(w2b);
        bf16x8 p10 = *(const bf16x8*)(w2b + 512);
        bf16x8 p01 = *(const bf16x8*)(w2b + 4096);
        bf16x8 p11 = *(const bf16x8*)(w2b + 4096 + 512);
        #pragma unroll
        for (int ks=0; ks<16; ++ks){
          bf16x8 c0 = p00, c1 = p10;
          p00 = p01; p10 = p11;
          if (ks+2 < 16){
            p01 = *(const bf16x8*)(w2b + (ks+2)*4096);
            p11 = *(const bf16x8*)(w2b + (ks+2)*4096 + 512);
          }
          bf16x8 h0 = *(const bf16x8*)&lds[32768 + (ks*2+l5)*1024 + (wt*64+l31)*8];
          bf16x8 h1 = *(const bf16x8*)&lds[32768 + (ks*2+l5)*1024 + (wt*64+32+l31)*8];
          a2[0][0] = MFMA32(c0, h0, a2[0][0]);
          a2[0][1] = MFMA32(c0, h1, a2[0][1]);
          a2[1][0] = MFMA32(c1, h0, a2[1][0]);
          a2[1][1] = MFMA32(c1, h1, a2[1][1]);
        }
      }
    }
  }
  // ---- rank-6 b2 correction: out += sum_e g[t,e] * b2[e,d] ----
  #pragma unroll
  for (int e=0;e<6;++e){
    #pragma unroll
    for (int a=0;a<2;++a){
      #pragma unroll
      for (int tt=0;tt<2;++tt){
        float g = wsl[(wt*64+tt*32+l31)*6 + e];
        #pragma unroll
        for (int rq=0;rq<4;++rq){
          float4 b4 = *(const float4*)(b2g + (size_t)e*256 + wh*64 + a*32 + rq*8 + l5*4);
          a2[a][tt][rq*4+0] += g*b4.x; a2[a][tt][rq*4+1] += g*b4.y;
          a2[a][tt][rq*4+2] += g*b4.z; a2[a][tt][rq*4+3] += g*b4.w;
        }
      }
    }
  }
  // ---- residual + store ----
  #pragma unroll
  for (int a=0;a<2;++a){
    #pragma unroll
    for (int tt=0;tt<2;++tt){
      int t = tb + wt*64 + tt*32 + l31;
      #pragma unroll
      for (int rq=0;rq<4;++rq){
        int d = wh*64 + a*32 + rq*8 + l5*4;
        float4 xv = *(const float4*)(xg + (size_t)t*256 + d);
        float4 o;
        o.x = xv.x + a2[a][tt][rq*4+0];
        o.y = xv.y + a2[a][tt][rq*4+1];
        o.z = xv.z + a2[a][tt][rq*4+2];
        o.w = xv.w + a2[a][tt][rq*4+3];
        *(float4*)(outp + (size_t)t*256 + d) = o;
      }
    }
  }
}

extern "C" void kernel_launch(void* const* d_in, const int* in_sizes, int n_in,
                              void* d_out, int out_size, void* d_ws, size_t ws_size,
                              hipStream_t stream){
  const float* x      = (const float*)d_in[0];
  const float* regime = (const float*)d_in[1];
  const float* ln_g   = (const float*)d_in[2];
  const float* ln_b   = (const float*)d_in[3];
  const float* w1     = (const float*)d_in[4];
  const float* b1     = (const float*)d_in[5];
  const float* w2     = (const float*)d_in[6];
  const float* b2     = (const float*)d_in[7];
  const float* rw1    = (const float*)d_in[8];
  const float* rb1    = (const float*)d_in[9];
  const float* rw2    = (const float*)d_in[10];
  const float* rb2    = (const float*)d_in[11];
  float* outp = (float*)d_out;
  char* ws = (char*)d_ws;

  u16*   w1t2 = (u16*)(ws + 0);          // 1,572,864
  u16*   w2t2 = (u16*)(ws + 1572864);    // 1,572,864
  u16*   rwh  = (u16*)(ws + 3145728);    // 131,072
  u16*   rwl  = (u16*)(ws + 3276800);    // 131,072
  float* regb = (float*)(ws + 3407872);  // 8,192
  u16*   xh   = (u16*)(ws + 3416064);    // 16,777,216
  u16*   xl   = (u16*)(ws + 20193280);   // 16,777,216 (dead after k_router)
  float* part = (float*)(ws + 20193280); // 98,304 — overlays xl, written after router
  float* hid  = (float*)(ws + 36970496); // 33,554,432
  float* selw = (float*)(ws + 70524928); // 786,432

  k_transpose<<<384,256,0,stream>>>(w1, w2, w1t2, w2t2);
  k_prep_rw1<<<264,256,0,stream>>>(rw1, rb1, regime, rwh, rwl, regb);
  k_ln<<<8192,256,0,stream>>>(x, ln_g, ln_b, xh, xl);
  k_router<<<512,256,0,stream>>>(xh, xl, rwh, rwl, regb, hid);
  k_logits<<<2048,256,0,stream>>>(hid, rw2, rb2, selw, part);
  k_aux<<<1,256,0,stream>>>(part, outp);
  k_experts<<<256,512,0,stream>>>(xh, w1t2, w2t2, b1, b2, selw, x, outp);
}

// Round 14
// 215.884 us; speedup vs baseline: 1.1454x; 1.1454x over previous
//
#include <hip/hip_runtime.h>
#include <cmath>

typedef unsigned short u16;
typedef __attribute__((ext_vector_type(8))) short bf16x8;
typedef __attribute__((ext_vector_type(4))) float f32x4;
typedef __attribute__((ext_vector_type(16))) float f32x16;

#define MFMA(a,b,c)   __builtin_amdgcn_mfma_f32_16x16x32_bf16((a),(b),(c),0,0,0)
#define MFMA32(a,b,c) __builtin_amdgcn_mfma_f32_32x32x16_bf16((a),(b),(c),0,0,0)

__device__ __forceinline__ float bf2f(u16 u){ return __uint_as_float(((unsigned)u)<<16); }
__device__ __forceinline__ u16 f2bf(float f){
  unsigned x = __float_as_uint(f);
  return (u16)((x + 0x7FFFu + ((x>>16)&1u)) >> 16);
}

__device__ __forceinline__ void gll16(const u16* g, u16* l){
  __builtin_amdgcn_global_load_lds((const __attribute__((address_space(1))) unsigned*)g,
                                   (__attribute__((address_space(3))) unsigned*)l, 16, 0, 0);
}

// ---------- prep: transpose + re-layout to slab-contiguous bf16 ----------
__global__ __launch_bounds__(256) void k_transpose(const float* __restrict__ w1,
        const float* __restrict__ w2, u16* __restrict__ w1t2, u16* __restrict__ w2t2){
  __shared__ u16 t[64][66];
  int b = blockIdx.x;
  int c0 = threadIdx.x & 63, r0 = threadIdx.x >> 6;
  if (b < 192){            // w1: src (D=256 x H=512)
    int e = b >> 5, tl = b & 31;
    int tr = (tl >> 3) << 6, tc = (tl & 7) << 6;
    const float* src = w1 + (size_t)e*131072;
    u16* dst = w1t2 + (size_t)e*131072;
    #pragma unroll
    for (int i=0;i<16;++i){
      int r = r0 + i*4;
      t[c0][r] = f2bf(src[(size_t)(tr+r)*512 + tc + c0]);
    }
    __syncthreads();
    #pragma unroll
    for (int i=0;i<16;++i){
      int cc = r0 + i*4;
      int h = tc + cc, d = tr + c0;
      dst[(size_t)((d>>4)*512 + h)*16 + (d&15)] = t[cc][c0];
    }
  } else {                 // w2: src (H=512 x D=256)
    int bb = b - 192;
    int e = bb >> 5, tl = bb & 31;
    int tr = (tl >> 2) << 6, tc = (tl & 3) << 6;
    const float* src = w2 + (size_t)e*131072;
    u16* dst = w2t2 + (size_t)e*131072;
    #pragma unroll
    for (int i=0;i<16;++i){
      int r = r0 + i*4;
      t[c0][r] = f2bf(src[(size_t)(tr+r)*256 + tc + c0]);
    }
    __syncthreads();
    #pragma unroll
    for (int i=0;i<16;++i){
      int cc = r0 + i*4;
      int d = tc + cc, h = tr + c0;
      dst[(size_t)((h>>4)*256 + d)*16 + (h&15)] = t[cc][c0];
    }
  }
}

// rw1 (261,256): first 256 rows -> [j][d] hi/lo bf16; rows 256..260 + rb1 folded into regb[b][j].
__global__ void k_prep_rw1(const float* __restrict__ rw1, const float* __restrict__ rb1,
                           const float* __restrict__ regime,
                           u16* __restrict__ rwh, u16* __restrict__ rwl,
                           float* __restrict__ regb){
  int idx = blockIdx.x*256 + threadIdx.x;
  if (idx < 65536){
    int dd = idx & 255, j = idx >> 8;
    float w = rw1[dd*256 + j];
    u16 hi = f2bf(w);
    rwh[idx] = hi;
    rwl[idx] = f2bf(w - bf2f(hi));
  } else {
    int i = idx - 65536; int j = i & 255, b = i >> 8;
    float v = rb1[j];
    #pragma unroll
    for (int r=0;r<5;++r) v += regime[b*5+r]*rw1[(256+r)*256 + j];
    regb[b*256 + j] = v;
  }
}

// ---------- LayerNorm: x -> xn hi/lo bf16 (wave per token) ----------
__global__ __launch_bounds__(256) void k_ln(const float* __restrict__ x,
        const float* __restrict__ g, const float* __restrict__ bta,
        u16* __restrict__ xh, u16* __restrict__ xl){
  int wv = threadIdx.x >> 6, lane = threadIdx.x & 63;
  int t = blockIdx.x*4 + wv;
  float4 v = ((const float4*)(x + (size_t)t*256))[lane];
  float s  = v.x+v.y+v.z+v.w;
  float ss = v.x*v.x+v.y*v.y+v.z*v.z+v.w*v.w;
  #pragma unroll
  for (int m=32;m>=1;m>>=1){ s += __shfl_xor(s,m); ss += __shfl_xor(ss,m); }
  float mu  = s*(1.f/256.f);
  float var = ss*(1.f/256.f) - mu*mu;
  float inv = 1.f / sqrtf(var + 1e-5f);
  float4 gv = ((const float4*)g)[lane];
  float4 bv = ((const float4*)bta)[lane];
  float xv[4] = {v.x,v.y,v.z,v.w};
  float gg[4] = {gv.x,gv.y,gv.z,gv.w};
  float bb[4] = {bv.x,bv.y,bv.z,bv.w};
  u16 hh[4], ll[4];
  #pragma unroll
  for (int q=0;q<4;++q){
    float xn = (xv[q]-mu)*inv*gg[q] + bb[q];
    u16 h = f2bf(xn);
    hh[q] = h;
    ll[q] = f2bf(xn - bf2f(h));
  }
  ((ushort4*)(xh + (size_t)t*256))[lane] = make_ushort4(hh[0],hh[1],hh[2],hh[3]);
  ((ushort4*)(xl + (size_t)t*256))[lane] = make_ushort4(ll[0],ll[1],ll[2],ll[3]);
}

// ---------- router GEMM + logits + top2 + aux, fused (hid stays in LDS) ----------
__global__ __launch_bounds__(256,2) void k_router(const u16* __restrict__ xh, const u16* __restrict__ xl,
        const u16* __restrict__ rwh, const u16* __restrict__ rwl,
        const float* __restrict__ regb,
        const float* __restrict__ rw2, const float* __restrict__ rb2,
        float* __restrict__ selw, float* __restrict__ partials){
  __shared__ __align__(16) u16 buf[33792];   // ash | asl, later reused as fbuf (f32 hid)
  __shared__ float psum[6], pcnt[6];
  u16* ash = buf;
  u16* asl = buf + 16896;
  float* fbuf = (float*)buf;                  // [t][j], row stride 257 f32
  int tid = threadIdx.x;
  if (tid < 6){ psum[tid]=0.f; pcnt[tid]=0.f; }
  int lane = tid & 63, wv = tid >> 6;
  int lr = lane & 15, lg = lane >> 4;
  int tb = blockIdx.x * 64;
  for (int c = tid; c < 2048; c += 256){
    int r = c >> 5, cc = c & 31;
    *(uint4*)(&ash[r*264 + cc*8]) = *(const uint4*)(xh + (size_t)(tb+r)*256 + cc*8);
    *(uint4*)(&asl[r*264 + cc*8]) = *(const uint4*)(xl + (size_t)(tb+r)*256 + cc*8);
  }
  __syncthreads();
  f32x4 acc[4][4];
  #pragma unroll
  for (int mf=0;mf<4;++mf)
    #pragma unroll
    for (int nf=0;nf<4;++nf) acc[mf][nf] = (f32x4){0.f,0.f,0.f,0.f};

  const u16* bhb = rwh + (size_t)wv*64*256;
  const u16* blb = rwl + (size_t)wv*64*256;
  #pragma unroll
  for (int kt=0;kt<8;++kt){
    bf16x8 ah[4], al[4], bh[4], bl[4];
    #pragma unroll
    for (int nf=0;nf<4;++nf){
      bh[nf] = *(const bf16x8*)(bhb + (size_t)(nf*16+lr)*256 + kt*32 + lg*8);
      bl[nf] = *(const bf16x8*)(blb + (size_t)(nf*16+lr)*256 + kt*32 + lg*8);
    }
    #pragma unroll
    for (int mf=0;mf<4;++mf){
      ah[mf] = *(const bf16x8*)(&ash[(mf*16+lr)*264 + kt*32 + lg*8]);
      al[mf] = *(const bf16x8*)(&asl[(mf*16+lr)*264 + kt*32 + lg*8]);
    }
    #pragma unroll
    for (int mf=0;mf<4;++mf)
      #pragma unroll
      for (int nf=0;nf<4;++nf){
        acc[mf][nf] = MFMA(ah[mf], bh[nf], acc[mf][nf]);
        acc[mf][nf] = MFMA(al[mf], bh[nf], acc[mf][nf]);
        acc[mf][nf] = MFMA(ah[mf], bl[nf], acc[mf][nf]);
      }
  }
  __syncthreads();   // all waves done reading ash/asl before fbuf overwrite
  int b = tb >> 12;
  #pragma unroll
  for (int mf=0;mf<4;++mf)
    #pragma unroll
    for (int nf=0;nf<4;++nf){
      int j = wv*64 + nf*16 + lr;
      float rbv = regb[b*256 + j];
      #pragma unroll
      for (int r=0;r<4;++r){
        int tl_ = mf*16 + lg*4 + r;
        float v = acc[mf][nf][r] + rbv;
        fbuf[tl_*257 + j] = v/(1.f+__expf(-v));
      }
    }
  __syncthreads();   // hid ready in LDS
  // ---- logits: 4 lanes per token ----
  int t4 = tid >> 2, part = tid & 3;
  float lacc[6] = {0.f,0.f,0.f,0.f,0.f,0.f};
  const float* hrow = fbuf + t4*257 + part*64;
  for (int jj=0;jj<64;++jj){
    float hv = hrow[jj];
    int j = part*64 + jj;
    #pragma unroll
    for (int e=0;e<6;++e) lacc[e] += hv*rw2[j*6+e];
  }
  #pragma unroll
  for (int m=1;m<4;m<<=1)
    #pragma unroll
    for (int e=0;e<6;++e) lacc[e] += __shfl_xor(lacc[e], m);
  if (part == 0){
    float lgv[6];
    #pragma unroll
    for (int e=0;e<6;++e) lgv[e] = lacc[e] + rb2[e];
    int i0=0; float v0=lgv[0];
    #pragma unroll
    for (int e=1;e<6;++e) if (lgv[e] > v0){ v0=lgv[e]; i0=e; }
    int i1=-1; float v1=-1e30f;
    #pragma unroll
    for (int e=0;e<6;++e) if (e!=i0 && lgv[e] > v1){ v1=lgv[e]; i1=e; }
    float ex = expf(v1-v0);
    float w0 = 1.f/(1.f+ex), w1 = ex/(1.f+ex);
    #pragma unroll
    for (int e=0;e<6;++e) selw[(size_t)(tb+t4)*6+e] = (e==i0)? w0 : (e==i1)? w1 : 0.f;
    float ps=0.f, p[6];
    #pragma unroll
    for (int e=0;e<6;++e){ p[e]=expf(lgv[e]-v0); ps+=p[e]; }
    float rinv = 1.f/ps;
    #pragma unroll
    for (int e=0;e<6;++e) atomicAdd(&psum[e], p[e]*rinv);
    atomicAdd(&pcnt[i0], 1.f);
  }
  __syncthreads();
  if (tid < 6){
    partials[blockIdx.x*12 + tid] = psum[tid];
    partials[blockIdx.x*12 + 6 + tid] = pcnt[tid];
  }
}

__global__ __launch_bounds__(256) void k_aux(const float* __restrict__ partials, float* __restrict__ outp){
  __shared__ float a[12];
  int tid = threadIdx.x;
  if (tid < 12) a[tid] = 0.f;
  __syncthreads();
  int col = tid & 15, seg = tid >> 4;
  if (col < 12){
    float s = 0.f;
    for (int i=seg; i<512; i+=16) s += partials[i*12+col];
    atomicAdd(&a[col], s);
  }
  __syncthreads();
  if (tid==0){
    float aux=0.f;
    #pragma unroll
    for (int e=0;e<6;++e) aux += a[e]*a[6+e];
    aux *= 0.01f*6.f/(32768.f*32768.f);
    outp[8388608] = aux;
  }
}

// ---------- fused all-expert MLP (r12 structure + cvt_pk epilogue) ----------
// 256 blocks (1/CU), 8 waves, launch_bounds(512,2). Slot-major LDS (conflict-free):
//   xs [s=0..31][tok=0..127] 16B cells -> u16 idx = s*1024 + tok*8            (64 KB)
//   hs [sh=0..31][tok=0..127] at +32768 (per h-half; stores g*silu)           (64 KB)
// Persistent acc = a2[4] only (gate folded into hs; b2 as rank-6 post-fix).
__global__ __launch_bounds__(512,2) void k_experts(const u16* __restrict__ xh,
        const u16* __restrict__ w1t2, const u16* __restrict__ w2t2,
        const float* __restrict__ b1g, const float* __restrict__ b2g,
        const float* __restrict__ selw, const float* __restrict__ xg,
        float* __restrict__ outp){
  __shared__ u16 lds[65536];
  __shared__ float wsl[768];
  int tid = threadIdx.x;
  int lane = tid & 63, wv = tid >> 6;
  int l31 = lane & 31, l5 = lane >> 5;
  int tb = blockIdx.x * 128;

  #pragma unroll
  for (int it=0; it<8; ++it){
    int gcell = it*512 + tid;
    int s = gcell >> 7, tok = gcell & 127;
    gll16(xh + (size_t)(tb+tok)*256 + s*8, lds + gcell*8);
  }
  for (int i=tid;i<768;i+=512) wsl[i] = selw[(size_t)tb*6 + i];
  __syncthreads();

  f32x16 a2[4];
  #pragma unroll
  for (int tt=0;tt<4;++tt) a2[tt] = (f32x16)(0.f);

  for (int e=0;e<6;++e){
    #pragma unroll
    for (int hh=0;hh<2;++hh){
      // ---- GEMM1: wave owns 32 h-rows, K=256, depth-4 prefetch ----
      f32x16 a1[4];
      #pragma unroll
      for (int tt=0;tt<4;++tt) a1[tt] = (f32x16)(0.f);
      const u16* w1b = w1t2 + (size_t)e*131072 + (size_t)(hh*256 + wv*32 + l31)*16 + l5*8;
      {
        bf16x8 p0 = *(const bf16x8*)(w1b);
        bf16x8 p1 = *(const bf16x8*)(w1b + 8192);
        bf16x8 p2 = *(const bf16x8*)(w1b + 16384);
        bf16x8 p3 = *(const bf16x8*)(w1b + 24576);
        #pragma unroll
        for (int ks=0; ks<16; ++ks){
          bf16x8 cur = p0; p0 = p1; p1 = p2; p2 = p3;
          if (ks+4 < 16) p3 = *(const bf16x8*)(w1b + (ks+4)*8192);
          #pragma unroll
          for (int tt=0;tt<4;++tt){
            bf16x8 bx = *(const bf16x8*)&lds[(ks*2+l5)*1024 + (tt*32+l31)*8];
            a1[tt] = MFMA32(cur, bx, a1[tt]);
          }
        }
      }
      __syncthreads();
      // ---- epilogue: bias + silu, scaled by gate -> hs (cvt_pk pack) ----
      #pragma unroll
      for (int rq=0;rq<4;++rq){
        float4 b4 = *(const float4*)(b1g + (size_t)e*512 + hh*256 + wv*32 + rq*8 + l5*4);
        float bb[4] = {b4.x,b4.y,b4.z,b4.w};
        #pragma unroll
        for (int tt=0;tt<4;++tt){
          float g = wsl[(tt*32+l31)*6 + e];
          float sv[4];
          #pragma unroll
          for (int q=0;q<4;++q){
            float v = a1[tt][rq*4+q] + bb[q];
            sv[q] = g * (v/(1.f+__expf(-v)));
          }
          unsigned pA, pB;
          asm("v_cvt_pk_bf16_f32 %0, %1, %2" : "=v"(pA) : "v"(sv[0]), "v"(sv[1]));
          asm("v_cvt_pk_bf16_f32 %0, %1, %2" : "=v"(pB) : "v"(sv[2]), "v"(sv[3]));
          *(uint2*)&lds[32768 + (wv*4+rq)*1024 + (tt*32+l31)*8 + l5*4] = make_uint2(pA,pB);
        }
      }
      __syncthreads();
      // ---- GEMM2: wave owns 32 d-rows, K = this h-half (256), accumulate into a2 ----
      const u16* w2b = w2t2 + (size_t)e*131072 + (size_t)(hh*16)*4096 + (size_t)(wv*32 + l31)*16 + l5*8;
      {
        bf16x8 p0 = *(const bf16x8*)(w2b);
        bf16x8 p1 = *(const bf16x8*)(w2b + 4096);
        bf16x8 p2 = *(const bf16x8*)(w2b + 8192);
        bf16x8 p3 = *(const bf16x8*)(w2b + 12288);
        #pragma unroll
        for (int ks=0; ks<16; ++ks){
          bf16x8 cur = p0; p0 = p1; p1 = p2; p2 = p3;
          if (ks+4 < 16) p3 = *(const bf16x8*)(w2b + (ks+4)*4096);
          #pragma unroll
          for (int tt=0;tt<4;++tt){
            bf16x8 hf = *(const bf16x8*)&lds[32768 + (ks*2+l5)*1024 + (tt*32+l31)*8];
            a2[tt] = MFMA32(cur, hf, a2[tt]);
          }
        }
      }
    }
  }
  // ---- rank-6 b2 correction ----
  #pragma unroll
  for (int e=0;e<6;++e){
    #pragma unroll
    for (int tt=0;tt<4;++tt){
      float g = wsl[(tt*32+l31)*6 + e];
      #pragma unroll
      for (int rq=0;rq<4;++rq){
        float4 b4 = *(const float4*)(b2g + (size_t)e*256 + wv*32 + rq*8 + l5*4);
        a2[tt][rq*4+0] += g*b4.x; a2[tt][rq*4+1] += g*b4.y;
        a2[tt][rq*4+2] += g*b4.z; a2[tt][rq*4+3] += g*b4.w;
      }
    }
  }
  // ---- residual + store ----
  #pragma unroll
  for (int tt=0;tt<4;++tt){
    int t = tb + tt*32 + l31;
    #pragma unroll
    for (int rq=0;rq<4;++rq){
      int d = wv*32 + rq*8 + l5*4;
      float4 xv = *(const float4*)(xg + (size_t)t*256 + d);
      float4 o;
      o.x = xv.x + a2[tt][rq*4+0];
      o.y = xv.y + a2[tt][rq*4+1];
      o.z = xv.z + a2[tt][rq*4+2];
      o.w = xv.w + a2[tt][rq*4+3];
      *(float4*)(outp + (size_t)t*256 + d) = o;
    }
  }
}

extern "C" void kernel_launch(void* const* d_in, const int* in_sizes, int n_in,
                              void* d_out, int out_size, void* d_ws, size_t ws_size,
                              hipStream_t stream){
  const float* x      = (const float*)d_in[0];
  const float* regime = (const float*)d_in[1];
  const float* ln_g   = (const float*)d_in[2];
  const float* ln_b   = (const float*)d_in[3];
  const float* w1     = (const float*)d_in[4];
  const float* b1     = (const float*)d_in[5];
  const float* w2     = (const float*)d_in[6];
  const float* b2     = (const float*)d_in[7];
  const float* rw1    = (const float*)d_in[8];
  const float* rb1    = (const float*)d_in[9];
  const float* rw2    = (const float*)d_in[10];
  const float* rb2    = (const float*)d_in[11];
  float* outp = (float*)d_out;
  char* ws = (char*)d_ws;

  u16*   w1t2 = (u16*)(ws + 0);          // 1,572,864
  u16*   w2t2 = (u16*)(ws + 1572864);    // 1,572,864
  u16*   rwh  = (u16*)(ws + 3145728);    // 131,072
  u16*   rwl  = (u16*)(ws + 3276800);    // 131,072
  float* regb = (float*)(ws + 3407872);  // 8,192
  u16*   xh   = (u16*)(ws + 3416064);    // 16,777,216
  u16*   xl   = (u16*)(ws + 20193280);   // 16,777,216 (dead after k_router)
  float* part = (float*)(ws + 36970496); // 24,576
  float* selw = (float*)(ws + 70524928); // 786,432

  k_transpose<<<384,256,0,stream>>>(w1, w2, w1t2, w2t2);
  k_prep_rw1<<<264,256,0,stream>>>(rw1, rb1, regime, rwh, rwl, regb);
  k_ln<<<8192,256,0,stream>>>(x, ln_g, ln_b, xh, xl);
  k_router<<<512,256,0,stream>>>(xh, xl, rwh, rwl, regb, rw2, rb2, selw, part);
  k_aux<<<1,256,0,stream>>>(part, outp);
  k_experts<<<256,512,0,stream>>>(xh, w1t2, w2t2, b1, b2, selw, x, outp);
}